// Round 1
// baseline (966.445 us; speedup 1.0000x reference)
//
#include <hip/hip_runtime.h>

#define DF 128
#define DO16 16

// ---------------- degree / norm ----------------
__global__ __launch_bounds__(256) void deg_hist_k(const int* __restrict__ dst, int e, int* __restrict__ deg) {
  int i = blockIdx.x * 256 + threadIdx.x;
  if (i < e) atomicAdd(&deg[dst[i]], 1);
}

__global__ __launch_bounds__(256) void dis_k(const int* __restrict__ deg, int n, float* __restrict__ dis) {
  int i = blockIdx.x * 256 + threadIdx.x;
  if (i < n) { int d = deg[i]; dis[i] = d > 0 ? rsqrtf((float)d) : 0.f; }
}

// ---------------- exclusive scan (3-phase) ----------------
__global__ __launch_bounds__(256) void scan1_k(const int* __restrict__ deg, int n, int* __restrict__ partials) {
  __shared__ int sm[256];
  int base = blockIdx.x * 1024;
  int s = 0;
#pragma unroll
  for (int j = 0; j < 4; j++) { int idx = base + threadIdx.x * 4 + j; if (idx < n) s += deg[idx]; }
  sm[threadIdx.x] = s; __syncthreads();
  for (int off = 128; off > 0; off >>= 1) {
    if (threadIdx.x < off) sm[threadIdx.x] += sm[threadIdx.x + off];
    __syncthreads();
  }
  if (threadIdx.x == 0) partials[blockIdx.x] = sm[0];
}

__global__ void scan2_k(int* partials, int nb) {
  if (threadIdx.x == 0 && blockIdx.x == 0) {
    int run = 0;
    for (int i = 0; i < nb; i++) { int v = partials[i]; partials[i] = run; run += v; }
  }
}

__global__ __launch_bounds__(256) void scan3_k(const int* __restrict__ deg, int n, int e,
                                               const int* __restrict__ partials,
                                               int* __restrict__ rowptr, int* __restrict__ cursor) {
  __shared__ int sm[256];
  int base = blockIdx.x * 1024;
  int loc[4]; int s = 0;
#pragma unroll
  for (int j = 0; j < 4; j++) {
    int idx = base + threadIdx.x * 4 + j;
    int v = (idx < n) ? deg[idx] : 0;
    loc[j] = s; s += v;
  }
  sm[threadIdx.x] = s; __syncthreads();
  int tsum = s;
  for (int off = 1; off < 256; off <<= 1) {
    int v = (threadIdx.x >= (unsigned)off) ? sm[threadIdx.x - off] : 0;
    __syncthreads();
    sm[threadIdx.x] += v;
    __syncthreads();
  }
  int excl = sm[threadIdx.x] - tsum + partials[blockIdx.x];
#pragma unroll
  for (int j = 0; j < 4; j++) {
    int idx = base + threadIdx.x * 4 + j;
    if (idx < n) { int v = excl + loc[j]; rowptr[idx] = v; cursor[idx] = v; }
  }
  if (blockIdx.x == 0 && threadIdx.x == 0) rowptr[n] = e;
}

__global__ __launch_bounds__(256) void csr_fill_k(const int* __restrict__ src, const int* __restrict__ dst, int e,
                                                  const float* __restrict__ dis, int* __restrict__ cursor,
                                                  int* __restrict__ col, float* __restrict__ val) {
  int i = blockIdx.x * 256 + threadIdx.x;
  if (i < e) {
    int s = src[i], d = dst[i];
    int p = atomicAdd(&cursor[d], 1);
    col[p] = s;
    val[p] = dis[s] * dis[d];
  }
}

// ---------------- SpMM D=128: one wave per node ----------------
__global__ __launch_bounds__(256) void spmm128_k(const float* __restrict__ hin, float* __restrict__ hout,
                                                 const int* __restrict__ rowptr, const int* __restrict__ col,
                                                 const float* __restrict__ val, int n) {
  int node = blockIdx.x * 4 + (threadIdx.x >> 6);
  int lane = threadIdx.x & 63;
  if (node >= n) return;
  int e0 = rowptr[node], e1 = rowptr[node + 1];
  float ax = 0.f, ay = 0.f;
  int ee = e0;
  for (; ee + 1 < e1; ee += 2) {
    int c0 = col[ee], c1 = col[ee + 1];
    float w0 = val[ee], w1 = val[ee + 1];
    float2 v0 = *reinterpret_cast<const float2*>(hin + (size_t)c0 * DF + 2 * lane);
    float2 v1 = *reinterpret_cast<const float2*>(hin + (size_t)c1 * DF + 2 * lane);
    ax = fmaf(w0, v0.x, ax); ay = fmaf(w0, v0.y, ay);
    ax = fmaf(w1, v1.x, ax); ay = fmaf(w1, v1.y, ay);
  }
  if (ee < e1) {
    int c0 = col[ee]; float w0 = val[ee];
    float2 v0 = *reinterpret_cast<const float2*>(hin + (size_t)c0 * DF + 2 * lane);
    ax = fmaf(w0, v0.x, ax); ay = fmaf(w0, v0.y, ay);
  }
  float2 r; r.x = ax; r.y = ay;
  *reinterpret_cast<float2*>(hout + (size_t)node * DF + 2 * lane) = r;
}

// ---------------- SpMM D=16 with fused add/bias ----------------
__global__ __launch_bounds__(256) void spmm16_k(const float* __restrict__ hin, int instride,
                                                const float* __restrict__ addsrc, int addstride,
                                                const float* __restrict__ bias,
                                                float* __restrict__ hout, int outstride,
                                                const int* __restrict__ rowptr, const int* __restrict__ col,
                                                const float* __restrict__ val, int n) {
  int t = blockIdx.x * 256 + threadIdx.x;
  int node = t >> 4, f = t & 15;
  if (node >= n) return;
  int e0 = rowptr[node], e1 = rowptr[node + 1];
  float acc = 0.f;
  for (int ee = e0; ee < e1; ++ee) {
    int c = col[ee]; float w = val[ee];
    acc = fmaf(w, hin[(size_t)c * instride + f], acc);
  }
  if (addsrc) acc += addsrc[(size_t)node * addstride + f];
  if (bias) acc += bias[f];
  hout[(size_t)node * outstride + f] = acc;
}

// ---------------- GEMM: [n,128] @ [128,128] with modes ----------------
// mode bit0: += Prev, bit1: += bias, bit2: relu
__global__ __launch_bounds__(256) void gemm128_k(const float* __restrict__ X, const float* __restrict__ W,
                                                 const float* __restrict__ Prev, const float* __restrict__ bias,
                                                 float* __restrict__ Out, int n, int mode) {
  __shared__ float Xs[32 * DF];   // 16 KB
  __shared__ float Ws[64 * DF];   // 32 KB
  int tid = threadIdx.x;
  int rbase = blockIdx.x * 32;
  {
    const float4* Xg = reinterpret_cast<const float4*>(X + (size_t)rbase * DF);
    float4* Xl = reinterpret_cast<float4*>(Xs);
#pragma unroll
    for (int i = 0; i < 4; i++) {
      int q = i * 256 + tid;
      int row = rbase + (q >> 5);
      float4 v = {0.f, 0.f, 0.f, 0.f};
      if (row < n) v = Xg[q];
      Xl[q] = v;
    }
  }
  int tx = tid & 31, ty = tid >> 5;
  int c0 = tx * 4, r0 = ty * 4;
  float acc[4][4] = {};
  for (int kk = 0; kk < 2; ++kk) {
    __syncthreads();
    const float4* Wg = reinterpret_cast<const float4*>(W + (size_t)kk * 64 * DF);
    float4* Wl = reinterpret_cast<float4*>(Ws);
#pragma unroll
    for (int i = 0; i < 8; i++) Wl[i * 256 + tid] = Wg[i * 256 + tid];
    __syncthreads();
#pragma unroll 8
    for (int k = 0; k < 64; k++) {
      float4 wv = *reinterpret_cast<const float4*>(&Ws[k * DF + c0]);
      float xv[4];
#pragma unroll
      for (int i = 0; i < 4; i++) xv[i] = Xs[(r0 + i) * DF + kk * 64 + k];
#pragma unroll
      for (int i = 0; i < 4; i++) {
        acc[i][0] = fmaf(xv[i], wv.x, acc[i][0]);
        acc[i][1] = fmaf(xv[i], wv.y, acc[i][1]);
        acc[i][2] = fmaf(xv[i], wv.z, acc[i][2]);
        acc[i][3] = fmaf(xv[i], wv.w, acc[i][3]);
      }
    }
  }
#pragma unroll
  for (int i = 0; i < 4; i++) {
    int r = rbase + r0 + i;
    if (r >= n) continue;
    float4 v; v.x = acc[i][0]; v.y = acc[i][1]; v.z = acc[i][2]; v.w = acc[i][3];
    if (mode & 1) {
      float4 p = *reinterpret_cast<const float4*>(Prev + (size_t)r * DF + c0);
      v.x += p.x; v.y += p.y; v.z += p.z; v.w += p.w;
    }
    if (mode & 2) { v.x += bias[c0]; v.y += bias[c0 + 1]; v.z += bias[c0 + 2]; v.w += bias[c0 + 3]; }
    if (mode & 4) { v.x = fmaxf(v.x, 0.f); v.y = fmaxf(v.y, 0.f); v.z = fmaxf(v.z, 0.f); v.w = fmaxf(v.w, 0.f); }
    *reinterpret_cast<float4*>(Out + (size_t)r * DF + c0) = v;
  }
}

// ---------------- GEMM: [n,128] @ packed W2 [128,64] -> GB[n,64] ----------------
__global__ __launch_bounds__(256) void gemm64_k(const float* __restrict__ X, const float* __restrict__ W2,
                                                float* __restrict__ GB, int n) {
  __shared__ float Xs[64 * DF];  // 32 KB
  __shared__ float Wc[DF * 64];  // 32 KB
  int tid = threadIdx.x;
  int rbase = blockIdx.x * 64;
#pragma unroll
  for (int i = 0; i < 32; i++) {
    int q = i * 256 + tid;           // 0..8191
    int d = q >> 6; int cc = q & 63; int k = cc >> 4; int c = cc & 15;
    Wc[q] = W2[((size_t)k * DF + d) * 16 + c];
  }
  {
    const float4* Xg = reinterpret_cast<const float4*>(X + (size_t)rbase * DF);
    float4* Xl = reinterpret_cast<float4*>(Xs);
#pragma unroll
    for (int i = 0; i < 8; i++) {
      int q = i * 256 + tid;
      int row = rbase + (q >> 5);
      float4 v = {0.f, 0.f, 0.f, 0.f};
      if (row < n) v = Xg[q];
      Xl[q] = v;
    }
  }
  __syncthreads();
  int tx = tid & 15, ty = tid >> 4;
  int c0 = tx * 4, r0 = ty * 4;
  float acc[4][4] = {};
#pragma unroll 8
  for (int k = 0; k < DF; k++) {
    float4 wv = *reinterpret_cast<const float4*>(&Wc[k * 64 + c0]);
    float xv[4];
#pragma unroll
    for (int i = 0; i < 4; i++) xv[i] = Xs[(r0 + i) * DF + k];
#pragma unroll
    for (int i = 0; i < 4; i++) {
      acc[i][0] = fmaf(xv[i], wv.x, acc[i][0]);
      acc[i][1] = fmaf(xv[i], wv.y, acc[i][1]);
      acc[i][2] = fmaf(xv[i], wv.z, acc[i][2]);
      acc[i][3] = fmaf(xv[i], wv.w, acc[i][3]);
    }
  }
#pragma unroll
  for (int i = 0; i < 4; i++) {
    int r = rbase + r0 + i;
    if (r >= n) continue;
    float4 v; v.x = acc[i][0]; v.y = acc[i][1]; v.z = acc[i][2]; v.w = acc[i][3];
    *reinterpret_cast<float4*>(GB + (size_t)r * 64 + c0) = v;
  }
}

extern "C" void kernel_launch(void* const* d_in, const int* in_sizes, int n_in,
                              void* d_out, int out_size, void* d_ws, size_t ws_size,
                              hipStream_t stream) {
  const float* x  = (const float*)d_in[0];
  const int*   ei = (const int*)d_in[1];
  const float* W1 = (const float*)d_in[2];
  const float* b1 = (const float*)d_in[3];
  const float* W2 = (const float*)d_in[4];
  const float* b2 = (const float*)d_in[5];
  float* out = (float*)d_out;

  const int n = in_sizes[0] / DF;
  const int e = in_sizes[1] / 2;
  const int* srcp = ei;
  const int* dstp = ei + e;

  char* ws = (char*)d_ws;
  size_t off = 0;
  auto alloc = [&](size_t bytes) -> void* {
    void* p = ws + off;
    off += (bytes + 255) & ~(size_t)255;
    return p;
  };
  float* U      = (float*)alloc((size_t)n * DF * 4);
  float* T      = (float*)alloc((size_t)n * DF * 4);
  int*   deg    = (int*)alloc((size_t)n * 4);
  float* dis    = (float*)alloc((size_t)n * 4);
  int*   rowptr = (int*)alloc((size_t)(n + 1) * 4);
  int*   cursor = (int*)alloc((size_t)n * 4);
  int*   partials = (int*)alloc(1024 * 4);
  int*   colb   = (int*)alloc((size_t)e * 4);
  float* valb   = (float*)alloc((size_t)e * 4);
  // layer-2 buffers alias T (T is dead after the final layer-1 GEMM)
  float* GB = T;                       // n x 64
  float* F0 = T + (size_t)n * 64;      // n x 16
  float* F1 = F0 + (size_t)n * 16;     // n x 16

  hipMemsetAsync(deg, 0, (size_t)n * 4, stream);

  int gE = (e + 255) / 256;
  int gN = (n + 255) / 256;
  int nb = (n + 1023) / 1024;

  deg_hist_k<<<gE, 256, 0, stream>>>(dstp, e, deg);
  dis_k<<<gN, 256, 0, stream>>>(deg, n, dis);
  scan1_k<<<nb, 256, 0, stream>>>(deg, n, partials);
  scan2_k<<<1, 64, 0, stream>>>(partials, nb);
  scan3_k<<<nb, 256, 0, stream>>>(deg, n, e, partials, rowptr, cursor);
  csr_fill_k<<<gE, 256, 0, stream>>>(srcp, dstp, e, dis, cursor, colb, valb);

  int gGemm128 = (n + 31) / 32;
  int gSpmm128 = (n + 3) / 4;
  int gSpmm16  = (n * 16 + 255) / 256;
  int gGemm64  = (n + 63) / 64;

  // ----- Layer 1 (Horner): out1 = xW0 + A(xW1 + A(xW2 + A(xW3))) -----
  gemm128_k<<<gGemm128, 256, 0, stream>>>(x, W1 + 3 * DF * DF, nullptr, nullptr, U, n, 0);
  spmm128_k<<<gSpmm128, 256, 0, stream>>>(U, T, rowptr, colb, valb, n);
  gemm128_k<<<gGemm128, 256, 0, stream>>>(x, W1 + 2 * DF * DF, T, nullptr, T, n, 1);
  spmm128_k<<<gSpmm128, 256, 0, stream>>>(T, U, rowptr, colb, valb, n);
  gemm128_k<<<gGemm128, 256, 0, stream>>>(x, W1 + 1 * DF * DF, U, nullptr, U, n, 1);
  spmm128_k<<<gSpmm128, 256, 0, stream>>>(U, T, rowptr, colb, valb, n);
  gemm128_k<<<gGemm128, 256, 0, stream>>>(x, W1 + 0 * DF * DF, T, b1, U, n, 1 | 2 | 4); // U = h1 = relu(...)

  // ----- Layer 2: g_k = h1 @ W2[k] all at once (packed), then Horner at D=16 -----
  gemm64_k<<<gGemm64, 256, 0, stream>>>(U, W2, GB, n);
  spmm16_k<<<gSpmm16, 256, 0, stream>>>(GB + 48, 64, GB + 32, 64, nullptr, F0, 16, rowptr, colb, valb, n);
  spmm16_k<<<gSpmm16, 256, 0, stream>>>(F0, 16, GB + 16, 64, nullptr, F1, 16, rowptr, colb, valb, n);
  spmm16_k<<<gSpmm16, 256, 0, stream>>>(F1, 16, GB + 0, 64, b2, out, 16, rowptr, colb, valb, n);
}

// Round 2
// 713.691 us; speedup vs baseline: 1.3542x; 1.3542x over previous
//
#include <hip/hip_runtime.h>

#define DF 128

typedef __attribute__((ext_vector_type(8))) short bf16x8;
typedef __attribute__((ext_vector_type(4))) float f32x4;

__device__ __forceinline__ ushort f2bf(float f) {
  uint u = __float_as_uint(f);
  u += 0x7fff + ((u >> 16) & 1);
  return (ushort)(u >> 16);
}
__device__ __forceinline__ float bfl(uint v) { return __uint_as_float(v << 16); }
__device__ __forceinline__ float bfh(uint v) { return __uint_as_float(v & 0xffff0000u); }
__device__ __forceinline__ float b2f(ushort s) { return __uint_as_float(((uint)s) << 16); }

// ---------------- degree / norm ----------------
__global__ __launch_bounds__(256) void deg_hist_k(const int* __restrict__ dst, int e, int* __restrict__ deg) {
  int i = blockIdx.x * 256 + threadIdx.x;
  if (i < e) atomicAdd(&deg[dst[i]], 1);
}

__global__ __launch_bounds__(256) void dis_k(const int* __restrict__ deg, int n, float* __restrict__ dis) {
  int i = blockIdx.x * 256 + threadIdx.x;
  if (i < n) { int d = deg[i]; dis[i] = d > 0 ? rsqrtf((float)d) : 0.f; }
}

// ---------------- exclusive scan (3-phase) ----------------
__global__ __launch_bounds__(256) void scan1_k(const int* __restrict__ deg, int n, int* __restrict__ partials) {
  __shared__ int sm[256];
  int base = blockIdx.x * 1024;
  int s = 0;
#pragma unroll
  for (int j = 0; j < 4; j++) { int idx = base + threadIdx.x * 4 + j; if (idx < n) s += deg[idx]; }
  sm[threadIdx.x] = s; __syncthreads();
  for (int off = 128; off > 0; off >>= 1) {
    if (threadIdx.x < off) sm[threadIdx.x] += sm[threadIdx.x + off];
    __syncthreads();
  }
  if (threadIdx.x == 0) partials[blockIdx.x] = sm[0];
}

__global__ void scan2_k(int* partials, int nb) {
  if (threadIdx.x == 0 && blockIdx.x == 0) {
    int run = 0;
    for (int i = 0; i < nb; i++) { int v = partials[i]; partials[i] = run; run += v; }
  }
}

__global__ __launch_bounds__(256) void scan3_k(const int* __restrict__ deg, int n, int e,
                                               const int* __restrict__ partials,
                                               int* __restrict__ rowptr, int* __restrict__ cursor) {
  __shared__ int sm[256];
  int base = blockIdx.x * 1024;
  int loc[4]; int s = 0;
#pragma unroll
  for (int j = 0; j < 4; j++) {
    int idx = base + threadIdx.x * 4 + j;
    int v = (idx < n) ? deg[idx] : 0;
    loc[j] = s; s += v;
  }
  sm[threadIdx.x] = s; __syncthreads();
  int tsum = s;
  for (int off = 1; off < 256; off <<= 1) {
    int v = (threadIdx.x >= (unsigned)off) ? sm[threadIdx.x - off] : 0;
    __syncthreads();
    sm[threadIdx.x] += v;
    __syncthreads();
  }
  int excl = sm[threadIdx.x] - tsum + partials[blockIdx.x];
#pragma unroll
  for (int j = 0; j < 4; j++) {
    int idx = base + threadIdx.x * 4 + j;
    if (idx < n) { int v = excl + loc[j]; rowptr[idx] = v; cursor[idx] = v; }
  }
  if (blockIdx.x == 0 && threadIdx.x == 0) rowptr[n] = e;
}

__global__ __launch_bounds__(256) void csr_fill_k(const int* __restrict__ src, const int* __restrict__ dst, int e,
                                                  const float* __restrict__ dis, int* __restrict__ cursor,
                                                  int* __restrict__ col, float* __restrict__ val) {
  int i = blockIdx.x * 256 + threadIdx.x;
  if (i < e) {
    int s = src[i], d = dst[i];
    int p = atomicAdd(&cursor[d], 1);
    col[p] = s;
    val[p] = dis[s] * dis[d];
  }
}

// ---------------- casts / weight prep ----------------
__global__ __launch_bounds__(256) void castx_k(const float* __restrict__ x, ushort* __restrict__ xb, int total4) {
  int i = blockIdx.x * 256 + threadIdx.x;
  if (i >= total4) return;
  float4 v = reinterpret_cast<const float4*>(x)[i];
  ushort4 s; s.x = f2bf(v.x); s.y = f2bf(v.y); s.z = f2bf(v.z); s.w = f2bf(v.w);
  reinterpret_cast<ushort4*>(xb)[i] = s;
}

// W1t[i][nn][kk] = W1[i][kk][nn]   (4 x 128 x 128)
// W2t[k4*16+c][kk] = W2[k4][kk][c] (64 x 128)
__global__ __launch_bounds__(256) void prepw_k(const float* __restrict__ W1, const float* __restrict__ W2,
                                               ushort* __restrict__ W1t, ushort* __restrict__ W2t) {
  int t = blockIdx.x * 256 + threadIdx.x;
  if (t < 4 * 128 * 128) {
    int i = t >> 14; int nn = (t >> 7) & 127; int kk = t & 127;
    W1t[t] = f2bf(W1[(i << 14) + kk * 128 + nn]);
  }
  if (t < 64 * 128) {
    int c64 = t >> 7; int kk = t & 127;
    int k4 = c64 >> 4; int c = c64 & 15;
    W2t[t] = f2bf(W2[k4 * 2048 + kk * 16 + c]);
  }
}

// ---------------- MFMA GEMM: Out[n,128] = X[n,128] @ W (+prev,+bias,relu) ----------------
// Wt is W^T row-major [128 n][128 k] bf16. Computes D^T via mfma(Wt_frag as A, X_frag as B).
// mode: bit0 add Prev (bf16 [n,128]), bit1 add bias (f32[128]), bit2 relu
__global__ __launch_bounds__(256) void gemm128b_k(const ushort* __restrict__ Xb, const ushort* __restrict__ Wt,
                                                  const ushort* __restrict__ Prev, const float* __restrict__ bias,
                                                  ushort* __restrict__ Out, int n, int mode) {
  int wid = threadIdx.x >> 6, lane = threadIdx.x & 63;
  int m = blockIdx.x * 64 + wid * 16 + (lane & 15);
  int kgrp = lane >> 4;                 // 0..3
  int mc = m < n ? m : n - 1;           // clamp for loads
  bf16x8 xf[4];
#pragma unroll
  for (int ks = 0; ks < 4; ks++)
    xf[ks] = *reinterpret_cast<const bf16x8*>(Xb + (size_t)mc * 128 + ks * 32 + kgrp * 8);
#pragma unroll
  for (int nt = 0; nt < 8; nt++) {
    f32x4 acc = {0.f, 0.f, 0.f, 0.f};
#pragma unroll
    for (int ks = 0; ks < 4; ks++) {
      bf16x8 wf = *reinterpret_cast<const bf16x8*>(Wt + (size_t)(nt * 16 + (lane & 15)) * 128 + ks * 32 + kgrp * 8);
      acc = __builtin_amdgcn_mfma_f32_16x16x32_bf16(wf, xf[ks], acc, 0, 0, 0);
    }
    int ncol = nt * 16 + kgrp * 4;
    if (mode & 1) {
      ushort4 p = *reinterpret_cast<const ushort4*>(Prev + (size_t)mc * 128 + ncol);
      acc[0] += b2f(p.x); acc[1] += b2f(p.y); acc[2] += b2f(p.z); acc[3] += b2f(p.w);
    }
    if (mode & 2) {
      float4 bv = *reinterpret_cast<const float4*>(bias + ncol);
      acc[0] += bv.x; acc[1] += bv.y; acc[2] += bv.z; acc[3] += bv.w;
    }
    if (mode & 4) {
      acc[0] = fmaxf(acc[0], 0.f); acc[1] = fmaxf(acc[1], 0.f);
      acc[2] = fmaxf(acc[2], 0.f); acc[3] = fmaxf(acc[3], 0.f);
    }
    if (m < n) {
      ushort4 st; st.x = f2bf(acc[0]); st.y = f2bf(acc[1]); st.z = f2bf(acc[2]); st.w = f2bf(acc[3]);
      *reinterpret_cast<ushort4*>(Out + (size_t)m * 128 + ncol) = st;
    }
  }
}

// ---------------- MFMA GEMM: GB[n,64] (f32) = H[n,128](bf16) @ W2pack ----------------
__global__ __launch_bounds__(256) void gemm64b_k(const ushort* __restrict__ Hb, const ushort* __restrict__ W2t,
                                                 float* __restrict__ GB, int n) {
  int wid = threadIdx.x >> 6, lane = threadIdx.x & 63;
  int m = blockIdx.x * 64 + wid * 16 + (lane & 15);
  int kgrp = lane >> 4;
  int mc = m < n ? m : n - 1;
  bf16x8 xf[4];
#pragma unroll
  for (int ks = 0; ks < 4; ks++)
    xf[ks] = *reinterpret_cast<const bf16x8*>(Hb + (size_t)mc * 128 + ks * 32 + kgrp * 8);
#pragma unroll
  for (int nt = 0; nt < 4; nt++) {
    f32x4 acc = {0.f, 0.f, 0.f, 0.f};
#pragma unroll
    for (int ks = 0; ks < 4; ks++) {
      bf16x8 wf = *reinterpret_cast<const bf16x8*>(W2t + (size_t)(nt * 16 + (lane & 15)) * 128 + ks * 32 + kgrp * 8);
      acc = __builtin_amdgcn_mfma_f32_16x16x32_bf16(wf, xf[ks], acc, 0, 0, 0);
    }
    int ncol = nt * 16 + kgrp * 4;
    if (m < n) {
      float4 st; st.x = acc[0]; st.y = acc[1]; st.z = acc[2]; st.w = acc[3];
      *reinterpret_cast<float4*>(GB + (size_t)m * 64 + ncol) = st;
    }
  }
}

// ---------------- SpMM D=128 bf16: one wave per node ----------------
__global__ __launch_bounds__(256) void spmm128b_k(const ushort* __restrict__ hin, ushort* __restrict__ hout,
                                                  const int* __restrict__ rowptr, const int* __restrict__ col,
                                                  const float* __restrict__ val, int n) {
  int node = blockIdx.x * 4 + (threadIdx.x >> 6);
  int lane = threadIdx.x & 63;
  if (node >= n) return;
  int e0 = rowptr[node], e1 = rowptr[node + 1];
  float ax = 0.f, ay = 0.f;
  int ee = e0;
  for (; ee + 4 <= e1; ee += 4) {
    int c0 = col[ee], c1 = col[ee + 1], c2 = col[ee + 2], c3 = col[ee + 3];
    float w0 = val[ee], w1 = val[ee + 1], w2 = val[ee + 2], w3 = val[ee + 3];
    uint v0 = *reinterpret_cast<const uint*>(hin + (size_t)c0 * 128 + lane * 2);
    uint v1 = *reinterpret_cast<const uint*>(hin + (size_t)c1 * 128 + lane * 2);
    uint v2 = *reinterpret_cast<const uint*>(hin + (size_t)c2 * 128 + lane * 2);
    uint v3 = *reinterpret_cast<const uint*>(hin + (size_t)c3 * 128 + lane * 2);
    ax = fmaf(w0, bfl(v0), ax); ay = fmaf(w0, bfh(v0), ay);
    ax = fmaf(w1, bfl(v1), ax); ay = fmaf(w1, bfh(v1), ay);
    ax = fmaf(w2, bfl(v2), ax); ay = fmaf(w2, bfh(v2), ay);
    ax = fmaf(w3, bfl(v3), ax); ay = fmaf(w3, bfh(v3), ay);
  }
  for (; ee < e1; ++ee) {
    int c = col[ee]; float w = val[ee];
    uint v = *reinterpret_cast<const uint*>(hin + (size_t)c * 128 + lane * 2);
    ax = fmaf(w, bfl(v), ax); ay = fmaf(w, bfh(v), ay);
  }
  uint st = (uint)f2bf(ax) | ((uint)f2bf(ay) << 16);
  *reinterpret_cast<uint*>(hout + (size_t)node * 128 + lane * 2) = st;
}

// ---------------- SpMM D=16 with fused add/bias (f32) ----------------
__global__ __launch_bounds__(256) void spmm16_k(const float* __restrict__ hin, int instride,
                                                const float* __restrict__ addsrc, int addstride,
                                                const float* __restrict__ bias,
                                                float* __restrict__ hout, int outstride,
                                                const int* __restrict__ rowptr, const int* __restrict__ col,
                                                const float* __restrict__ val, int n) {
  int t = blockIdx.x * 256 + threadIdx.x;
  int node = t >> 4, f = t & 15;
  if (node >= n) return;
  int e0 = rowptr[node], e1 = rowptr[node + 1];
  float acc = 0.f;
  int ee = e0;
  for (; ee + 2 <= e1; ee += 2) {
    int c0 = col[ee], c1 = col[ee + 1];
    float w0 = val[ee], w1 = val[ee + 1];
    float v0 = hin[(size_t)c0 * instride + f];
    float v1 = hin[(size_t)c1 * instride + f];
    acc = fmaf(w0, v0, acc); acc = fmaf(w1, v1, acc);
  }
  if (ee < e1) {
    int c = col[ee]; float w = val[ee];
    acc = fmaf(w, hin[(size_t)c * instride + f], acc);
  }
  if (addsrc) acc += addsrc[(size_t)node * addstride + f];
  if (bias) acc += bias[f];
  hout[(size_t)node * outstride + f] = acc;
}

extern "C" void kernel_launch(void* const* d_in, const int* in_sizes, int n_in,
                              void* d_out, int out_size, void* d_ws, size_t ws_size,
                              hipStream_t stream) {
  const float* x  = (const float*)d_in[0];
  const int*   ei = (const int*)d_in[1];
  const float* W1 = (const float*)d_in[2];
  const float* b1 = (const float*)d_in[3];
  const float* W2 = (const float*)d_in[4];
  const float* b2 = (const float*)d_in[5];
  float* out = (float*)d_out;

  const int n = in_sizes[0] / DF;
  const int e = in_sizes[1] / 2;
  const int* srcp = ei;
  const int* dstp = ei + e;

  char* ws = (char*)d_ws;
  size_t off = 0;
  auto alloc = [&](size_t bytes) -> void* {
    void* p = ws + off;
    off += (bytes + 255) & ~(size_t)255;
    return p;
  };
  ushort* Xb    = (ushort*)alloc((size_t)n * DF * 2);   // x in bf16
  ushort* U     = (ushort*)alloc((size_t)n * DF * 2);   // feature ping
  ushort* T     = (ushort*)alloc((size_t)n * DF * 2);   // feature pong (also GB f32 n x 64)
  int*   deg    = (int*)alloc((size_t)n * 4);
  float* dis    = (float*)alloc((size_t)n * 4);
  int*   rowptr = (int*)alloc((size_t)(n + 1) * 4);
  int*   cursor = (int*)alloc((size_t)n * 4);
  int*   partials = (int*)alloc(1024 * 4);
  int*   colb   = (int*)alloc((size_t)e * 4);
  float* valb   = (float*)alloc((size_t)e * 4);
  ushort* W1t   = (ushort*)alloc(4 * 128 * 128 * 2);
  ushort* W2t   = (ushort*)alloc(64 * 128 * 2);
  // aliases for layer 2 (dead buffers reused)
  float* GB = (float*)T;                 // n x 64 f32 (same byte size as T)
  float* F0 = (float*)Xb;                // n x 16 f32
  float* F1 = F0 + (size_t)n * 16;       // n x 16 f32 (fits: 2*n*16*4 <= n*128*2)

  hipMemsetAsync(deg, 0, (size_t)n * 4, stream);

  int gE = (e + 255) / 256;
  int gN = (n + 255) / 256;
  int nb = (n + 1023) / 1024;

  deg_hist_k<<<gE, 256, 0, stream>>>(dstp, e, deg);
  dis_k<<<gN, 256, 0, stream>>>(deg, n, dis);
  scan1_k<<<nb, 256, 0, stream>>>(deg, n, partials);
  scan2_k<<<1, 64, 0, stream>>>(partials, nb);
  scan3_k<<<nb, 256, 0, stream>>>(deg, n, e, partials, rowptr, cursor);
  csr_fill_k<<<gE, 256, 0, stream>>>(srcp, dstp, e, dis, cursor, colb, valb);

  castx_k<<<(n * 32 + 255) / 256, 256, 0, stream>>>(x, Xb, n * 32);
  prepw_k<<<256, 256, 0, stream>>>(W1, W2, W1t, W2t);

  int gGemm = (n + 63) / 64;
  int gSpmm128 = (n + 3) / 4;
  int gSpmm16 = (n * 16 + 255) / 256;

  // ----- Layer 1 (Horner): h1 = relu(xW0 + A(xW1 + A(xW2 + A(xW3))) + b1) -----
  gemm128b_k<<<gGemm, 256, 0, stream>>>(Xb, W1t + 3 * DF * DF, nullptr, nullptr, U, n, 0);
  spmm128b_k<<<gSpmm128, 256, 0, stream>>>(U, T, rowptr, colb, valb, n);
  gemm128b_k<<<gGemm, 256, 0, stream>>>(Xb, W1t + 2 * DF * DF, T, nullptr, T, n, 1);
  spmm128b_k<<<gSpmm128, 256, 0, stream>>>(T, U, rowptr, colb, valb, n);
  gemm128b_k<<<gGemm, 256, 0, stream>>>(Xb, W1t + 1 * DF * DF, U, nullptr, U, n, 1);
  spmm128b_k<<<gSpmm128, 256, 0, stream>>>(U, T, rowptr, colb, valb, n);
  gemm128b_k<<<gGemm, 256, 0, stream>>>(Xb, W1t + 0 * DF * DF, T, b1, U, n, 1 | 2 | 4); // U = h1 (bf16)

  // ----- Layer 2: GB = h1 @ W2pack (f32), then Horner at D=16 -----
  gemm64b_k<<<gGemm, 256, 0, stream>>>(U, W2t, GB, n);
  spmm16_k<<<gSpmm16, 256, 0, stream>>>(GB + 48, 64, GB + 32, 64, nullptr, F0, 16, rowptr, colb, valb, n);
  spmm16_k<<<gSpmm16, 256, 0, stream>>>(F0, 16, GB + 16, 64, nullptr, F1, 16, rowptr, colb, valb, n);
  spmm16_k<<<gSpmm16, 256, 0, stream>>>(F1, 16, GB + 0, 64, b2, out, 16, rowptr, colb, valb, n);
}

// Round 3
// 622.606 us; speedup vs baseline: 1.5523x; 1.1463x over previous
//
#include <hip/hip_runtime.h>

#define DF 128

typedef __attribute__((ext_vector_type(8))) short bf16x8;
typedef __attribute__((ext_vector_type(4))) float f32x4;

__device__ __forceinline__ ushort f2bf(float f) {
  uint u = __float_as_uint(f);
  u += 0x7fff + ((u >> 16) & 1);
  return (ushort)(u >> 16);
}
__device__ __forceinline__ float bfl(uint v) { return __uint_as_float(v << 16); }
__device__ __forceinline__ float bfh(uint v) { return __uint_as_float(v & 0xffff0000u); }
__device__ __forceinline__ float b2f(ushort s) { return __uint_as_float(((uint)s) << 16); }

// ---------------- degree hist + per-edge rank ----------------
__global__ __launch_bounds__(256) void deg_hist_k(const int* __restrict__ dst, int e,
                                                  int* __restrict__ deg, int* __restrict__ rank) {
  int i = blockIdx.x * 256 + threadIdx.x;
  if (i < e) rank[i] = atomicAdd(&deg[dst[i]], 1);
}

__global__ __launch_bounds__(256) void dis_k(const int* __restrict__ deg, int n, float* __restrict__ dis) {
  int i = blockIdx.x * 256 + threadIdx.x;
  if (i < n) { int d = deg[i]; dis[i] = d > 0 ? rsqrtf((float)d) : 0.f; }
}

// ---------------- exclusive scan (3-phase) ----------------
__global__ __launch_bounds__(256) void scan1_k(const int* __restrict__ deg, int n, int* __restrict__ partials) {
  __shared__ int sm[256];
  int base = blockIdx.x * 1024;
  int s = 0;
#pragma unroll
  for (int j = 0; j < 4; j++) { int idx = base + threadIdx.x * 4 + j; if (idx < n) s += deg[idx]; }
  sm[threadIdx.x] = s; __syncthreads();
  for (int off = 128; off > 0; off >>= 1) {
    if (threadIdx.x < off) sm[threadIdx.x] += sm[threadIdx.x + off];
    __syncthreads();
  }
  if (threadIdx.x == 0) partials[blockIdx.x] = sm[0];
}

__global__ void scan2_k(int* partials, int nb) {
  if (threadIdx.x == 0 && blockIdx.x == 0) {
    int run = 0;
    for (int i = 0; i < nb; i++) { int v = partials[i]; partials[i] = run; run += v; }
  }
}

__global__ __launch_bounds__(256) void scan3_k(const int* __restrict__ deg, int n, int e,
                                               const int* __restrict__ partials,
                                               int* __restrict__ rowptr) {
  __shared__ int sm[256];
  int base = blockIdx.x * 1024;
  int loc[4]; int s = 0;
#pragma unroll
  for (int j = 0; j < 4; j++) {
    int idx = base + threadIdx.x * 4 + j;
    int v = (idx < n) ? deg[idx] : 0;
    loc[j] = s; s += v;
  }
  sm[threadIdx.x] = s; __syncthreads();
  int tsum = s;
  for (int off = 1; off < 256; off <<= 1) {
    int v = (threadIdx.x >= (unsigned)off) ? sm[threadIdx.x - off] : 0;
    __syncthreads();
    sm[threadIdx.x] += v;
    __syncthreads();
  }
  int excl = sm[threadIdx.x] - tsum + partials[blockIdx.x];
#pragma unroll
  for (int j = 0; j < 4; j++) {
    int idx = base + threadIdx.x * 4 + j;
    if (idx < n) rowptr[idx] = excl + loc[j];
  }
  if (blockIdx.x == 0 && threadIdx.x == 0) rowptr[n] = e;
}

// atomic-free: p = rowptr[dst] + rank; one packed 8B scatter (col, val-bits)
__global__ __launch_bounds__(256) void csr_fill_k(const int* __restrict__ src, const int* __restrict__ dst, int e,
                                                  const int* __restrict__ rank, const int* __restrict__ rowptr,
                                                  const float* __restrict__ dis, int2* __restrict__ ev) {
  int i = blockIdx.x * 256 + threadIdx.x;
  if (i < e) {
    int s = src[i], d = dst[i];
    int p = rowptr[d] + rank[i];
    float w = dis[s] * dis[d];
    int2 pk; pk.x = s; pk.y = __float_as_int(w);
    ev[p] = pk;
  }
}

// ---------------- casts / weight prep ----------------
__global__ __launch_bounds__(256) void castx_k(const float* __restrict__ x, ushort* __restrict__ xb, int total4) {
  int i = blockIdx.x * 256 + threadIdx.x;
  if (i >= total4) return;
  float4 v = reinterpret_cast<const float4*>(x)[i];
  ushort4 s; s.x = f2bf(v.x); s.y = f2bf(v.y); s.z = f2bf(v.z); s.w = f2bf(v.w);
  reinterpret_cast<ushort4*>(xb)[i] = s;
}

// W1t[i][nn][kk] = W1[i][kk][nn]   (4 x 128 x 128)
// W2t[k4*16+c][kk] = W2[k4][kk][c] (64 x 128)
__global__ __launch_bounds__(256) void prepw_k(const float* __restrict__ W1, const float* __restrict__ W2,
                                               ushort* __restrict__ W1t, ushort* __restrict__ W2t) {
  int t = blockIdx.x * 256 + threadIdx.x;
  if (t < 4 * 128 * 128) {
    int i = t >> 14; int nn = (t >> 7) & 127; int kk = t & 127;
    W1t[t] = f2bf(W1[(i << 14) + kk * 128 + nn]);
  }
  if (t < 64 * 128) {
    int c64 = t >> 7; int kk = t & 127;
    int k4 = c64 >> 4; int c = c64 & 15;
    W2t[t] = f2bf(W2[k4 * 2048 + kk * 16 + c]);
  }
}

// ---------------- MFMA GEMM: Out[n,128] = X[n,128] @ W (+prev,+bias,relu) ----------------
__global__ __launch_bounds__(256) void gemm128b_k(const ushort* __restrict__ Xb, const ushort* __restrict__ Wt,
                                                  const ushort* __restrict__ Prev, const float* __restrict__ bias,
                                                  ushort* __restrict__ Out, int n, int mode) {
  int wid = threadIdx.x >> 6, lane = threadIdx.x & 63;
  int m = blockIdx.x * 64 + wid * 16 + (lane & 15);
  int kgrp = lane >> 4;                 // 0..3
  int mc = m < n ? m : n - 1;           // clamp for loads
  bf16x8 xf[4];
#pragma unroll
  for (int ks = 0; ks < 4; ks++)
    xf[ks] = *reinterpret_cast<const bf16x8*>(Xb + (size_t)mc * 128 + ks * 32 + kgrp * 8);
#pragma unroll
  for (int nt = 0; nt < 8; nt++) {
    f32x4 acc = {0.f, 0.f, 0.f, 0.f};
#pragma unroll
    for (int ks = 0; ks < 4; ks++) {
      bf16x8 wf = *reinterpret_cast<const bf16x8*>(Wt + (size_t)(nt * 16 + (lane & 15)) * 128 + ks * 32 + kgrp * 8);
      acc = __builtin_amdgcn_mfma_f32_16x16x32_bf16(wf, xf[ks], acc, 0, 0, 0);
    }
    int ncol = nt * 16 + kgrp * 4;
    if (mode & 1) {
      ushort4 p = *reinterpret_cast<const ushort4*>(Prev + (size_t)mc * 128 + ncol);
      acc[0] += b2f(p.x); acc[1] += b2f(p.y); acc[2] += b2f(p.z); acc[3] += b2f(p.w);
    }
    if (mode & 2) {
      float4 bv = *reinterpret_cast<const float4*>(bias + ncol);
      acc[0] += bv.x; acc[1] += bv.y; acc[2] += bv.z; acc[3] += bv.w;
    }
    if (mode & 4) {
      acc[0] = fmaxf(acc[0], 0.f); acc[1] = fmaxf(acc[1], 0.f);
      acc[2] = fmaxf(acc[2], 0.f); acc[3] = fmaxf(acc[3], 0.f);
    }
    if (m < n) {
      ushort4 st; st.x = f2bf(acc[0]); st.y = f2bf(acc[1]); st.z = f2bf(acc[2]); st.w = f2bf(acc[3]);
      *reinterpret_cast<ushort4*>(Out + (size_t)m * 128 + ncol) = st;
    }
  }
}

// ---------------- MFMA GEMM: GB[n,64] (f32) = H[n,128](bf16) @ W2pack ----------------
__global__ __launch_bounds__(256) void gemm64b_k(const ushort* __restrict__ Hb, const ushort* __restrict__ W2t,
                                                 float* __restrict__ GB, int n) {
  int wid = threadIdx.x >> 6, lane = threadIdx.x & 63;
  int m = blockIdx.x * 64 + wid * 16 + (lane & 15);
  int kgrp = lane >> 4;
  int mc = m < n ? m : n - 1;
  bf16x8 xf[4];
#pragma unroll
  for (int ks = 0; ks < 4; ks++)
    xf[ks] = *reinterpret_cast<const bf16x8*>(Hb + (size_t)mc * 128 + ks * 32 + kgrp * 8);
#pragma unroll
  for (int nt = 0; nt < 4; nt++) {
    f32x4 acc = {0.f, 0.f, 0.f, 0.f};
#pragma unroll
    for (int ks = 0; ks < 4; ks++) {
      bf16x8 wf = *reinterpret_cast<const bf16x8*>(W2t + (size_t)(nt * 16 + (lane & 15)) * 128 + ks * 32 + kgrp * 8);
      acc = __builtin_amdgcn_mfma_f32_16x16x32_bf16(wf, xf[ks], acc, 0, 0, 0);
    }
    int ncol = nt * 16 + kgrp * 4;
    if (m < n) {
      float4 st; st.x = acc[0]; st.y = acc[1]; st.z = acc[2]; st.w = acc[3];
      *reinterpret_cast<float4*>(GB + (size_t)m * 64 + ncol) = st;
    }
  }
}

// ---------------- SpMM D=128 bf16: one wave per node, predicated unroll-8 ----------------
__global__ __launch_bounds__(256) void spmm128b_k(const ushort* __restrict__ hin, ushort* __restrict__ hout,
                                                  const int* __restrict__ rowptr, const int2* __restrict__ ev,
                                                  int n) {
  int node = blockIdx.x * 4 + (threadIdx.x >> 6);
  int lane = threadIdx.x & 63;
  if (node >= n) return;
  int e0 = rowptr[node], e1 = rowptr[node + 1];
  float ax = 0.f, ay = 0.f;
  for (int ee = e0; ee < e1; ee += 8) {
    int2 ed[8];
#pragma unroll
    for (int j = 0; j < 8; j++) {
      int idx = ee + j;
      int2 t = ev[idx < e1 ? idx : e0];
      if (idx >= e1) t.y = 0;
      ed[j] = t;
    }
    uint v[8];
#pragma unroll
    for (int j = 0; j < 8; j++)
      v[j] = *reinterpret_cast<const uint*>(hin + (size_t)ed[j].x * 128 + lane * 2);
#pragma unroll
    for (int j = 0; j < 8; j++) {
      float w = __int_as_float(ed[j].y);
      ax = fmaf(w, bfl(v[j]), ax); ay = fmaf(w, bfh(v[j]), ay);
    }
  }
  uint st = (uint)f2bf(ax) | ((uint)f2bf(ay) << 16);
  *reinterpret_cast<uint*>(hout + (size_t)node * 128 + lane * 2) = st;
}

// ---------------- SpMM D=16 with fused add/bias (f32), predicated unroll-4 ----------------
__global__ __launch_bounds__(256) void spmm16_k(const float* __restrict__ hin, int instride,
                                                const float* __restrict__ addsrc, int addstride,
                                                const float* __restrict__ bias,
                                                float* __restrict__ hout, int outstride,
                                                const int* __restrict__ rowptr, const int2* __restrict__ ev,
                                                int n) {
  int t = blockIdx.x * 256 + threadIdx.x;
  int node = t >> 4, f = t & 15;
  if (node >= n) return;
  int e0 = rowptr[node], e1 = rowptr[node + 1];
  float acc = 0.f;
  for (int ee = e0; ee < e1; ee += 4) {
    int2 ed[4];
#pragma unroll
    for (int j = 0; j < 4; j++) {
      int idx = ee + j;
      int2 tt = ev[idx < e1 ? idx : e0];
      if (idx >= e1) tt.y = 0;
      ed[j] = tt;
    }
    float v[4];
#pragma unroll
    for (int j = 0; j < 4; j++) v[j] = hin[(size_t)ed[j].x * instride + f];
#pragma unroll
    for (int j = 0; j < 4; j++) acc = fmaf(__int_as_float(ed[j].y), v[j], acc);
  }
  if (addsrc) acc += addsrc[(size_t)node * addstride + f];
  if (bias) acc += bias[f];
  hout[(size_t)node * outstride + f] = acc;
}

extern "C" void kernel_launch(void* const* d_in, const int* in_sizes, int n_in,
                              void* d_out, int out_size, void* d_ws, size_t ws_size,
                              hipStream_t stream) {
  const float* x  = (const float*)d_in[0];
  const int*   ei = (const int*)d_in[1];
  const float* W1 = (const float*)d_in[2];
  const float* b1 = (const float*)d_in[3];
  const float* W2 = (const float*)d_in[4];
  const float* b2 = (const float*)d_in[5];
  float* out = (float*)d_out;

  const int n = in_sizes[0] / DF;
  const int e = in_sizes[1] / 2;
  const int* srcp = ei;
  const int* dstp = ei + e;

  char* ws = (char*)d_ws;
  size_t off = 0;
  auto alloc = [&](size_t bytes) -> void* {
    void* p = ws + off;
    off += (bytes + 255) & ~(size_t)255;
    return p;
  };
  ushort* Xb    = (ushort*)alloc((size_t)n * DF * 2);   // x in bf16
  ushort* U     = (ushort*)alloc((size_t)n * DF * 2);   // feature ping
  ushort* T     = (ushort*)alloc((size_t)n * DF * 2);   // feature pong (also GB f32 n x 64)
  int*   deg    = (int*)alloc((size_t)n * 4);
  float* dis    = (float*)alloc((size_t)n * 4);
  int*   rowptr = (int*)alloc((size_t)(n + 1) * 4);
  int*   rank   = (int*)alloc((size_t)e * 4);
  int*   partials = (int*)alloc(1024 * 4);
  int2*  ev     = (int2*)alloc((size_t)e * 8);
  ushort* W1t   = (ushort*)alloc(4 * 128 * 128 * 2);
  ushort* W2t   = (ushort*)alloc(64 * 128 * 2);
  // aliases for layer 2 (dead buffers reused)
  float* GB = (float*)T;                 // n x 64 f32
  float* F0 = (float*)Xb;                // n x 16 f32
  float* F1 = F0 + (size_t)n * 16;       // n x 16 f32

  hipMemsetAsync(deg, 0, (size_t)n * 4, stream);

  int gE = (e + 255) / 256;
  int gN = (n + 255) / 256;
  int nb = (n + 1023) / 1024;

  deg_hist_k<<<gE, 256, 0, stream>>>(dstp, e, deg, rank);
  dis_k<<<gN, 256, 0, stream>>>(deg, n, dis);
  scan1_k<<<nb, 256, 0, stream>>>(deg, n, partials);
  scan2_k<<<1, 64, 0, stream>>>(partials, nb);
  scan3_k<<<nb, 256, 0, stream>>>(deg, n, e, partials, rowptr);
  csr_fill_k<<<gE, 256, 0, stream>>>(srcp, dstp, e, rank, rowptr, dis, ev);

  castx_k<<<(n * 32 + 255) / 256, 256, 0, stream>>>(x, Xb, n * 32);
  prepw_k<<<256, 256, 0, stream>>>(W1, W2, W1t, W2t);

  int gGemm = (n + 63) / 64;
  int gSpmm128 = (n + 3) / 4;
  int gSpmm16 = (n * 16 + 255) / 256;

  // ----- Layer 1 (Horner): h1 = relu(xW0 + A(xW1 + A(xW2 + A(xW3))) + b1) -----
  gemm128b_k<<<gGemm, 256, 0, stream>>>(Xb, W1t + 3 * DF * DF, nullptr, nullptr, U, n, 0);
  spmm128b_k<<<gSpmm128, 256, 0, stream>>>(U, T, rowptr, ev, n);
  gemm128b_k<<<gGemm, 256, 0, stream>>>(Xb, W1t + 2 * DF * DF, T, nullptr, T, n, 1);
  spmm128b_k<<<gSpmm128, 256, 0, stream>>>(T, U, rowptr, ev, n);
  gemm128b_k<<<gGemm, 256, 0, stream>>>(Xb, W1t + 1 * DF * DF, U, nullptr, U, n, 1);
  spmm128b_k<<<gSpmm128, 256, 0, stream>>>(U, T, rowptr, ev, n);
  gemm128b_k<<<gGemm, 256, 0, stream>>>(Xb, W1t + 0 * DF * DF, T, b1, U, n, 1 | 2 | 4); // U = h1 (bf16)

  // ----- Layer 2: GB = h1 @ W2pack (f32), then Horner at D=16 -----
  gemm64b_k<<<gGemm, 256, 0, stream>>>(U, W2t, GB, n);
  spmm16_k<<<gSpmm16, 256, 0, stream>>>(GB + 48, 64, GB + 32, 64, nullptr, F0, 16, rowptr, ev, n);
  spmm16_k<<<gSpmm16, 256, 0, stream>>>(F0, 16, GB + 16, 64, nullptr, F1, 16, rowptr, ev, n);
  spmm16_k<<<gSpmm16, 256, 0, stream>>>(F1, 16, GB + 0, 64, b2, out, 16, rowptr, ev, n);
}

// Round 4
// 588.347 us; speedup vs baseline: 1.6426x; 1.0582x over previous
//
#include <hip/hip_runtime.h>

#define DF 128

typedef __attribute__((ext_vector_type(8))) short bf16x8;
typedef __attribute__((ext_vector_type(4))) float f32x4;

__device__ __forceinline__ ushort f2bf(float f) {
  uint u = __float_as_uint(f);
  u += 0x7fff + ((u >> 16) & 1);
  return (ushort)(u >> 16);
}
__device__ __forceinline__ float bfl(uint v) { return __uint_as_float(v << 16); }
__device__ __forceinline__ float bfh(uint v) { return __uint_as_float(v & 0xffff0000u); }
__device__ __forceinline__ float b2f(ushort s) { return __uint_as_float(((uint)s) << 16); }

// ---------------- degree hist + per-edge rank ----------------
__global__ __launch_bounds__(256) void deg_hist_k(const int* __restrict__ dst, int e,
                                                  int* __restrict__ deg, int* __restrict__ rank) {
  int i = blockIdx.x * 256 + threadIdx.x;
  if (i < e) rank[i] = atomicAdd(&deg[dst[i]], 1);
}

__global__ __launch_bounds__(256) void dis_k(const int* __restrict__ deg, int n, float* __restrict__ dis) {
  int i = blockIdx.x * 256 + threadIdx.x;
  if (i < n) { int d = deg[i]; dis[i] = d > 0 ? rsqrtf((float)d) : 0.f; }
}

// ---------------- exclusive scan (3-phase) ----------------
__global__ __launch_bounds__(256) void scan1_k(const int* __restrict__ deg, int n, int* __restrict__ partials) {
  __shared__ int sm[256];
  int base = blockIdx.x * 1024;
  int s = 0;
#pragma unroll
  for (int j = 0; j < 4; j++) { int idx = base + threadIdx.x * 4 + j; if (idx < n) s += deg[idx]; }
  sm[threadIdx.x] = s; __syncthreads();
  for (int off = 128; off > 0; off >>= 1) {
    if (threadIdx.x < off) sm[threadIdx.x] += sm[threadIdx.x + off];
    __syncthreads();
  }
  if (threadIdx.x == 0) partials[blockIdx.x] = sm[0];
}

__global__ void scan2_k(int* partials, int nb) {
  if (threadIdx.x == 0 && blockIdx.x == 0) {
    int run = 0;
    for (int i = 0; i < nb; i++) { int v = partials[i]; partials[i] = run; run += v; }
  }
}

__global__ __launch_bounds__(256) void scan3_k(const int* __restrict__ deg, int n, int e,
                                               const int* __restrict__ partials,
                                               int* __restrict__ rowptr) {
  __shared__ int sm[256];
  int base = blockIdx.x * 1024;
  int loc[4]; int s = 0;
#pragma unroll
  for (int j = 0; j < 4; j++) {
    int idx = base + threadIdx.x * 4 + j;
    int v = (idx < n) ? deg[idx] : 0;
    loc[j] = s; s += v;
  }
  sm[threadIdx.x] = s; __syncthreads();
  int tsum = s;
  for (int off = 1; off < 256; off <<= 1) {
    int v = (threadIdx.x >= (unsigned)off) ? sm[threadIdx.x - off] : 0;
    __syncthreads();
    sm[threadIdx.x] += v;
    __syncthreads();
  }
  int excl = sm[threadIdx.x] - tsum + partials[blockIdx.x];
#pragma unroll
  for (int j = 0; j < 4; j++) {
    int idx = base + threadIdx.x * 4 + j;
    if (idx < n) rowptr[idx] = excl + loc[j];
  }
  if (blockIdx.x == 0 && threadIdx.x == 0) rowptr[n] = e;
}

// atomic-free: p = rowptr[dst] + rank; one packed 8B scatter (col, val-bits)
__global__ __launch_bounds__(256) void csr_fill_k(const int* __restrict__ src, const int* __restrict__ dst, int e,
                                                  const int* __restrict__ rank, const int* __restrict__ rowptr,
                                                  const float* __restrict__ dis, int2* __restrict__ ev) {
  int i = blockIdx.x * 256 + threadIdx.x;
  if (i < e) {
    int s = src[i], d = dst[i];
    int p = rowptr[d] + rank[i];
    float w = dis[s] * dis[d];
    int2 pk; pk.x = s; pk.y = __float_as_int(w);
    ev[p] = pk;
  }
}

// ---------------- casts / weight prep ----------------
__global__ __launch_bounds__(256) void castx_k(const float* __restrict__ x, ushort* __restrict__ xb, int total4) {
  int i = blockIdx.x * 256 + threadIdx.x;
  if (i >= total4) return;
  float4 v = reinterpret_cast<const float4*>(x)[i];
  ushort4 s; s.x = f2bf(v.x); s.y = f2bf(v.y); s.z = f2bf(v.z); s.w = f2bf(v.w);
  reinterpret_cast<ushort4*>(xb)[i] = s;
}

// W1t[i][nn][kk] = W1[i][kk][nn]   (4 x 128 x 128)
// W2t[k4*16+c][kk] = W2[k4][kk][c] (64 x 128)
__global__ __launch_bounds__(256) void prepw_k(const float* __restrict__ W1, const float* __restrict__ W2,
                                               ushort* __restrict__ W1t, ushort* __restrict__ W2t) {
  int t = blockIdx.x * 256 + threadIdx.x;
  if (t < 4 * 128 * 128) {
    int i = t >> 14; int nn = (t >> 7) & 127; int kk = t & 127;
    W1t[t] = f2bf(W1[(i << 14) + kk * 128 + nn]);
  }
  if (t < 64 * 128) {
    int c64 = t >> 7; int kk = t & 127;
    int k4 = c64 >> 4; int c = c64 & 15;
    W2t[t] = f2bf(W2[k4 * 2048 + kk * 16 + c]);
  }
}

// ---------------- MFMA GEMM (z3 = Xb @ W3) ----------------
__global__ __launch_bounds__(256) void gemm128b_k(const ushort* __restrict__ Xb, const ushort* __restrict__ Wt,
                                                  ushort* __restrict__ Out, int n) {
  int wid = threadIdx.x >> 6, lane = threadIdx.x & 63;
  int m = blockIdx.x * 64 + wid * 16 + (lane & 15);
  int kgrp = lane >> 4;
  int mc = m < n ? m : n - 1;
  bf16x8 xf[4];
#pragma unroll
  for (int ks = 0; ks < 4; ks++)
    xf[ks] = *reinterpret_cast<const bf16x8*>(Xb + (size_t)mc * 128 + ks * 32 + kgrp * 8);
#pragma unroll
  for (int nt = 0; nt < 8; nt++) {
    f32x4 acc = {0.f, 0.f, 0.f, 0.f};
#pragma unroll
    for (int ks = 0; ks < 4; ks++) {
      bf16x8 wf = *reinterpret_cast<const bf16x8*>(Wt + (size_t)(nt * 16 + (lane & 15)) * 128 + ks * 32 + kgrp * 8);
      acc = __builtin_amdgcn_mfma_f32_16x16x32_bf16(wf, xf[ks], acc, 0, 0, 0);
    }
    int ncol = nt * 16 + kgrp * 4;
    if (m < n) {
      ushort4 st; st.x = f2bf(acc[0]); st.y = f2bf(acc[1]); st.z = f2bf(acc[2]); st.w = f2bf(acc[3]);
      *reinterpret_cast<ushort4*>(Out + (size_t)m * 128 + ncol) = st;
    }
  }
}

// ---------------- Fused hop: h_out = Xb@Wk + A*h_in  (mode1: +b1, relu, GB=h1@W2pack) ----------------
__global__ __launch_bounds__(256) void hop_fused_k(
    const ushort* __restrict__ hin, const ushort* __restrict__ Xb,
    const ushort* __restrict__ Wt, const float* __restrict__ b1,
    ushort* __restrict__ hout, const ushort* __restrict__ W2t, ushort* __restrict__ GB,
    const int* __restrict__ rowptr, const int2* __restrict__ ev, int n, int mode) {
  __shared__ ushort sp[16][136];   // padded: row stride 272 B
  int tid = threadIdx.x;
  int w = tid >> 6, lane = tid & 63;

  // ---- Phase A: gather A*h_in for 16 nodes (wave-per-node, 4 nodes/wave) ----
#pragma unroll
  for (int i = 0; i < 4; i++) {
    int ln = w * 4 + i;
    int node = blockIdx.x * 16 + ln;
    float ax = 0.f, ay = 0.f;
    if (node < n) {
      int e0 = rowptr[node], e1 = rowptr[node + 1];
      for (int ee = e0; ee < e1; ee += 8) {
        int2 ed[8];
#pragma unroll
        for (int j = 0; j < 8; j++) {
          int idx = ee + j;
          int2 t = ev[idx < e1 ? idx : e0];
          if (idx >= e1) t.y = 0;
          ed[j] = t;
        }
        uint v[8];
#pragma unroll
        for (int j = 0; j < 8; j++)
          v[j] = *reinterpret_cast<const uint*>(hin + (size_t)ed[j].x * 128 + lane * 2);
#pragma unroll
        for (int j = 0; j < 8; j++) {
          float wt = __int_as_float(ed[j].y);
          ax = fmaf(wt, bfl(v[j]), ax); ay = fmaf(wt, bfh(v[j]), ay);
        }
      }
    }
    uint pk = (uint)f2bf(ax) | ((uint)f2bf(ay) << 16);
    *reinterpret_cast<uint*>(&sp[ln][lane * 2]) = pk;
  }
  __syncthreads();

  // ---- Phase B: acc = Xb @ Wk (MFMA) + sp ----
  int kgrp = lane >> 4, l15 = lane & 15;
  int m = blockIdx.x * 16 + l15;
  int mc = m < n ? m : n - 1;
  bf16x8 xf[4];
#pragma unroll
  for (int ks = 0; ks < 4; ks++)
    xf[ks] = *reinterpret_cast<const bf16x8*>(Xb + (size_t)mc * 128 + ks * 32 + kgrp * 8);
  f32x4 accv[2];
#pragma unroll
  for (int t = 0; t < 2; t++) {
    int nt = w * 2 + t;
    f32x4 acc = {0.f, 0.f, 0.f, 0.f};
#pragma unroll
    for (int ks = 0; ks < 4; ks++) {
      bf16x8 wf = *reinterpret_cast<const bf16x8*>(Wt + (size_t)(nt * 16 + l15) * 128 + ks * 32 + kgrp * 8);
      acc = __builtin_amdgcn_mfma_f32_16x16x32_bf16(wf, xf[ks], acc, 0, 0, 0);
    }
    int ncol = nt * 16 + kgrp * 4;
    ushort4 a = *reinterpret_cast<const ushort4*>(&sp[l15][ncol]);
    acc[0] += b2f(a.x); acc[1] += b2f(a.y); acc[2] += b2f(a.z); acc[3] += b2f(a.w);
    if (mode) {
      float4 bv = *reinterpret_cast<const float4*>(b1 + ncol);
      acc[0] = fmaxf(acc[0] + bv.x, 0.f); acc[1] = fmaxf(acc[1] + bv.y, 0.f);
      acc[2] = fmaxf(acc[2] + bv.z, 0.f); acc[3] = fmaxf(acc[3] + bv.w, 0.f);
    } else if (m < n) {
      ushort4 st; st.x = f2bf(acc[0]); st.y = f2bf(acc[1]); st.z = f2bf(acc[2]); st.w = f2bf(acc[3]);
      *reinterpret_cast<ushort4*>(hout + (size_t)m * 128 + ncol) = st;
    }
    accv[t] = acc;
  }

  // ---- Phase C (last hop): GB = h1 @ W2pack, h1 via LDS ----
  if (mode) {
    __syncthreads();   // all sp reads done
#pragma unroll
    for (int t = 0; t < 2; t++) {
      int ncol = (w * 2 + t) * 16 + kgrp * 4;
      ushort4 st; st.x = f2bf(accv[t][0]); st.y = f2bf(accv[t][1]);
      st.z = f2bf(accv[t][2]); st.w = f2bf(accv[t][3]);
      *reinterpret_cast<ushort4*>(&sp[l15][ncol]) = st;
    }
    __syncthreads();
    f32x4 acc = {0.f, 0.f, 0.f, 0.f};
#pragma unroll
    for (int ks = 0; ks < 4; ks++) {
      bf16x8 af = *reinterpret_cast<const bf16x8*>(W2t + (size_t)(w * 16 + l15) * 128 + ks * 32 + kgrp * 8);
      bf16x8 bf = *reinterpret_cast<const bf16x8*>(&sp[l15][ks * 32 + kgrp * 8]);
      acc = __builtin_amdgcn_mfma_f32_16x16x32_bf16(af, bf, acc, 0, 0, 0);
    }
    if (m < n) {
      int c = w * 16 + kgrp * 4;
      ushort4 st; st.x = f2bf(acc[0]); st.y = f2bf(acc[1]); st.z = f2bf(acc[2]); st.w = f2bf(acc[3]);
      *reinterpret_cast<ushort4*>(GB + (size_t)m * 64 + c) = st;
    }
  }
}

// ---------------- SpMM D=16 bf16 (8 threads/node, 2 cols each) ----------------
__global__ __launch_bounds__(256) void spmm16b_k(
    const ushort* __restrict__ in, int instride, int ioff,
    const ushort* __restrict__ add, int addstride, int aoff,
    const float* __restrict__ b2, float* __restrict__ outf, ushort* __restrict__ outb,
    const int* __restrict__ rowptr, const int2* __restrict__ ev, int n) {
  int t = blockIdx.x * 256 + threadIdx.x;
  int node = t >> 3, cp = t & 7;
  if (node >= n) return;
  int e0 = rowptr[node], e1 = rowptr[node + 1];
  float a0 = 0.f, a1 = 0.f;
  for (int ee = e0; ee < e1; ee += 4) {
    int2 ed[4];
#pragma unroll
    for (int j = 0; j < 4; j++) {
      int idx = ee + j;
      int2 tt = ev[idx < e1 ? idx : e0];
      if (idx >= e1) tt.y = 0;
      ed[j] = tt;
    }
    uint v[4];
#pragma unroll
    for (int j = 0; j < 4; j++)
      v[j] = *reinterpret_cast<const uint*>(in + (size_t)ed[j].x * instride + ioff + cp * 2);
#pragma unroll
    for (int j = 0; j < 4; j++) {
      float wt = __int_as_float(ed[j].y);
      a0 = fmaf(wt, bfl(v[j]), a0); a1 = fmaf(wt, bfh(v[j]), a1);
    }
  }
  uint av = *reinterpret_cast<const uint*>(add + (size_t)node * addstride + aoff + cp * 2);
  a0 += bfl(av); a1 += bfh(av);
  if (outf) {
    float2 st; st.x = a0 + b2[cp * 2]; st.y = a1 + b2[cp * 2 + 1];
    *reinterpret_cast<float2*>(outf + (size_t)node * 16 + cp * 2) = st;
  } else {
    uint pk = (uint)f2bf(a0) | ((uint)f2bf(a1) << 16);
    *reinterpret_cast<uint*>(outb + (size_t)node * 16 + cp * 2) = pk;
  }
}

extern "C" void kernel_launch(void* const* d_in, const int* in_sizes, int n_in,
                              void* d_out, int out_size, void* d_ws, size_t ws_size,
                              hipStream_t stream) {
  const float* x  = (const float*)d_in[0];
  const int*   ei = (const int*)d_in[1];
  const float* W1 = (const float*)d_in[2];
  const float* b1 = (const float*)d_in[3];
  const float* W2 = (const float*)d_in[4];
  const float* b2 = (const float*)d_in[5];
  float* out = (float*)d_out;

  const int n = in_sizes[0] / DF;
  const int e = in_sizes[1] / 2;
  const int* srcp = ei;
  const int* dstp = ei + e;

  char* ws = (char*)d_ws;
  size_t off = 0;
  auto alloc = [&](size_t bytes) -> void* {
    void* p = ws + off;
    off += (bytes + 255) & ~(size_t)255;
    return p;
  };
  ushort* Xb    = (ushort*)alloc((size_t)n * DF * 2);   // x bf16; later F0/F1
  ushort* U     = (ushort*)alloc((size_t)n * DF * 2);   // feature ping
  ushort* T     = (ushort*)alloc((size_t)n * DF * 2);   // feature pong; later GB (n x 64 bf16)
  int*   deg    = (int*)alloc((size_t)n * 4);
  float* dis    = (float*)alloc((size_t)n * 4);
  int*   rowptr = (int*)alloc((size_t)(n + 1) * 4);
  int*   rank   = (int*)alloc((size_t)e * 4);
  int*   partials = (int*)alloc(1024 * 4);
  int2*  ev     = (int2*)alloc((size_t)e * 8);
  ushort* W1t   = (ushort*)alloc(4 * 128 * 128 * 2);
  ushort* W2t   = (ushort*)alloc(64 * 128 * 2);
  // aliases (dead buffers reused)
  ushort* GB = T;                        // n x 64 bf16
  ushort* F0 = Xb;                       // n x 16 bf16
  ushort* F1 = Xb + (size_t)n * 16;      // n x 16 bf16

  hipMemsetAsync(deg, 0, (size_t)n * 4, stream);

  int gE = (e + 255) / 256;
  int gN = (n + 255) / 256;
  int nb = (n + 1023) / 1024;

  deg_hist_k<<<gE, 256, 0, stream>>>(dstp, e, deg, rank);
  dis_k<<<gN, 256, 0, stream>>>(deg, n, dis);
  scan1_k<<<nb, 256, 0, stream>>>(deg, n, partials);
  scan2_k<<<1, 64, 0, stream>>>(partials, nb);
  scan3_k<<<nb, 256, 0, stream>>>(deg, n, e, partials, rowptr);
  csr_fill_k<<<gE, 256, 0, stream>>>(srcp, dstp, e, rank, rowptr, dis, ev);

  castx_k<<<(n * 32 + 255) / 256, 256, 0, stream>>>(x, Xb, n * 32);
  prepw_k<<<256, 256, 0, stream>>>(W1, W2, W1t, W2t);

  int gGemm = (n + 63) / 64;
  int gHop  = (n + 15) / 16;
  int gS16  = (n * 8 + 255) / 256;

  // ----- Layer 1 Horner, fused: h_run = Xb@W3; 3x (h_run = Xb@Wk + A h_run) -----
  gemm128b_k<<<gGemm, 256, 0, stream>>>(Xb, W1t + 3 * DF * DF, U, n);
  hop_fused_k<<<gHop, 256, 0, stream>>>(U, Xb, W1t + 2 * DF * DF, nullptr, T, nullptr, nullptr,
                                        rowptr, ev, n, 0);
  hop_fused_k<<<gHop, 256, 0, stream>>>(T, Xb, W1t + 1 * DF * DF, nullptr, U, nullptr, nullptr,
                                        rowptr, ev, n, 0);
  // last hop: +b1, relu, and GB = h1 @ W2pack (h1 never hits global)
  hop_fused_k<<<gHop, 256, 0, stream>>>(U, Xb, W1t + 0 * DF * DF, b1, nullptr, W2t, GB,
                                        rowptr, ev, n, 1);

  // ----- Layer 2 Horner at D=16 (bf16 chain) -----
  spmm16b_k<<<gS16, 256, 0, stream>>>(GB, 64, 48, GB, 64, 32, nullptr, nullptr, F0, rowptr, ev, n);
  spmm16b_k<<<gS16, 256, 0, stream>>>(F0, 16, 0,  GB, 64, 16, nullptr, nullptr, F1, rowptr, ev, n);
  spmm16b_k<<<gS16, 256, 0, stream>>>(F1, 16, 0,  GB, 64, 0,  b2, out, nullptr, rowptr, ev, n);
}

// Round 5
// 543.252 us; speedup vs baseline: 1.7790x; 1.0830x over previous
//
#include <hip/hip_runtime.h>

#define DF 128

typedef __attribute__((ext_vector_type(8))) short bf16x8;
typedef __attribute__((ext_vector_type(4))) float f32x4;

__device__ __forceinline__ ushort f2bf(float f) {
  uint u = __float_as_uint(f);
  u += 0x7fff + ((u >> 16) & 1);
  return (ushort)(u >> 16);
}
__device__ __forceinline__ float bfl(uint v) { return __uint_as_float(v << 16); }
__device__ __forceinline__ float bfh(uint v) { return __uint_as_float(v & 0xffff0000u); }
__device__ __forceinline__ float b2f(ushort s) { return __uint_as_float(((uint)s) << 16); }

// ---------------- degree hist + per-edge rank ----------------
__global__ __launch_bounds__(256) void deg_hist_k(const int* __restrict__ dst, int e,
                                                  int* __restrict__ deg, int* __restrict__ rank) {
  int i = blockIdx.x * 256 + threadIdx.x;
  if (i < e) rank[i] = atomicAdd(&deg[dst[i]], 1);
}

__global__ __launch_bounds__(256) void dis_k(const int* __restrict__ deg, int n, float* __restrict__ dis) {
  int i = blockIdx.x * 256 + threadIdx.x;
  if (i < n) { int d = deg[i]; dis[i] = d > 0 ? rsqrtf((float)d) : 0.f; }
}

// ---------------- exclusive scan (3-phase) ----------------
__global__ __launch_bounds__(256) void scan1_k(const int* __restrict__ deg, int n, int* __restrict__ partials) {
  __shared__ int sm[256];
  int base = blockIdx.x * 1024;
  int s = 0;
#pragma unroll
  for (int j = 0; j < 4; j++) { int idx = base + threadIdx.x * 4 + j; if (idx < n) s += deg[idx]; }
  sm[threadIdx.x] = s; __syncthreads();
  for (int off = 128; off > 0; off >>= 1) {
    if (threadIdx.x < off) sm[threadIdx.x] += sm[threadIdx.x + off];
    __syncthreads();
  }
  if (threadIdx.x == 0) partials[blockIdx.x] = sm[0];
}

__global__ void scan2_k(int* partials, int nb) {
  if (threadIdx.x == 0 && blockIdx.x == 0) {
    int run = 0;
    for (int i = 0; i < nb; i++) { int v = partials[i]; partials[i] = run; run += v; }
  }
}

__global__ __launch_bounds__(256) void scan3_k(const int* __restrict__ deg, int n, int e,
                                               const int* __restrict__ partials,
                                               int* __restrict__ rowptr) {
  __shared__ int sm[256];
  int base = blockIdx.x * 1024;
  int loc[4]; int s = 0;
#pragma unroll
  for (int j = 0; j < 4; j++) {
    int idx = base + threadIdx.x * 4 + j;
    int v = (idx < n) ? deg[idx] : 0;
    loc[j] = s; s += v;
  }
  sm[threadIdx.x] = s; __syncthreads();
  int tsum = s;
  for (int off = 1; off < 256; off <<= 1) {
    int v = (threadIdx.x >= (unsigned)off) ? sm[threadIdx.x - off] : 0;
    __syncthreads();
    sm[threadIdx.x] += v;
    __syncthreads();
  }
  int excl = sm[threadIdx.x] - tsum + partials[blockIdx.x];
#pragma unroll
  for (int j = 0; j < 4; j++) {
    int idx = base + threadIdx.x * 4 + j;
    if (idx < n) rowptr[idx] = excl + loc[j];
  }
  if (blockIdx.x == 0 && threadIdx.x == 0) rowptr[n] = e;
}

// atomic-free: p = rowptr[dst] + rank; one packed 8B scatter (col, val-bits)
__global__ __launch_bounds__(256) void csr_fill_k(const int* __restrict__ src, const int* __restrict__ dst, int e,
                                                  const int* __restrict__ rank, const int* __restrict__ rowptr,
                                                  const float* __restrict__ dis, int2* __restrict__ ev) {
  int i = blockIdx.x * 256 + threadIdx.x;
  if (i < e) {
    int s = src[i], d = dst[i];
    int p = rowptr[d] + rank[i];
    float w = dis[s] * dis[d];
    int2 pk; pk.x = s; pk.y = __float_as_int(w);
    ev[p] = pk;
  }
}

// ---------------- casts / weight prep ----------------
__global__ __launch_bounds__(256) void castx_k(const float* __restrict__ x, ushort* __restrict__ xb, int total4) {
  int i = blockIdx.x * 256 + threadIdx.x;
  if (i >= total4) return;
  float4 v = reinterpret_cast<const float4*>(x)[i];
  ushort4 s; s.x = f2bf(v.x); s.y = f2bf(v.y); s.z = f2bf(v.z); s.w = f2bf(v.w);
  reinterpret_cast<ushort4*>(xb)[i] = s;
}

// W1t[i][nn][kk] = W1[i][kk][nn]   (4 x 128 x 128)
// W2t[k4*16+c][kk] = W2[k4][kk][c] (64 x 128)
__global__ __launch_bounds__(256) void prepw_k(const float* __restrict__ W1, const float* __restrict__ W2,
                                               ushort* __restrict__ W1t, ushort* __restrict__ W2t) {
  int t = blockIdx.x * 256 + threadIdx.x;
  if (t < 4 * 128 * 128) {
    int i = t >> 14; int nn = (t >> 7) & 127; int kk = t & 127;
    W1t[t] = f2bf(W1[(i << 14) + kk * 128 + nn]);
  }
  if (t < 64 * 128) {
    int c64 = t >> 7; int kk = t & 127;
    int k4 = c64 >> 4; int c = c64 & 15;
    W2t[t] = f2bf(W2[k4 * 2048 + kk * 16 + c]);
  }
}

// ---------------- MFMA GEMM: Out = Xb @ W (+Prev if mode&1) ----------------
__global__ __launch_bounds__(256) void gemm128b_k(const ushort* __restrict__ Xb, const ushort* __restrict__ Wt,
                                                  const ushort* __restrict__ Prev,
                                                  ushort* __restrict__ Out, int n, int mode) {
  int wid = threadIdx.x >> 6, lane = threadIdx.x & 63;
  int l15 = lane & 15, kgrp = lane >> 4;
  int m = blockIdx.x * 64 + wid * 16 + l15;
  int mc = m < n ? m : n - 1;
  bf16x8 xf[4];
#pragma unroll
  for (int ks = 0; ks < 4; ks++)
    xf[ks] = *reinterpret_cast<const bf16x8*>(Xb + (size_t)mc * 128 + ks * 32 + kgrp * 8);
#pragma unroll
  for (int nt = 0; nt < 8; nt++) {
    f32x4 acc = {0.f, 0.f, 0.f, 0.f};
#pragma unroll
    for (int ks = 0; ks < 4; ks++) {
      bf16x8 wf = *reinterpret_cast<const bf16x8*>(Wt + (size_t)(nt * 16 + l15) * 128 + ks * 32 + kgrp * 8);
      acc = __builtin_amdgcn_mfma_f32_16x16x32_bf16(wf, xf[ks], acc, 0, 0, 0);
    }
    int ncol = nt * 16 + kgrp * 4;
    if (mode & 1) {
      ushort4 p = *reinterpret_cast<const ushort4*>(Prev + (size_t)mc * 128 + ncol);
      acc[0] += b2f(p.x); acc[1] += b2f(p.y); acc[2] += b2f(p.z); acc[3] += b2f(p.w);
    }
    if (m < n) {
      ushort4 st; st.x = f2bf(acc[0]); st.y = f2bf(acc[1]); st.z = f2bf(acc[2]); st.w = f2bf(acc[3]);
      *reinterpret_cast<ushort4*>(Out + (size_t)m * 128 + ncol) = st;
    }
  }
}

// ---------------- Final: h1 = relu(Xb@W0 + Prev + b1) in LDS; GB = h1 @ W2pack ----------------
__global__ __launch_bounds__(256) void gemm_last_k(const ushort* __restrict__ Xb, const ushort* __restrict__ W0t,
                                                   const ushort* __restrict__ Prev, const float* __restrict__ b1,
                                                   const ushort* __restrict__ W2t, ushort* __restrict__ GB, int n) {
  __shared__ ushort sp[4][16][136];
  int wid = threadIdx.x >> 6, lane = threadIdx.x & 63;
  int l15 = lane & 15, kgrp = lane >> 4;
  int m = blockIdx.x * 64 + wid * 16 + l15;
  int mc = m < n ? m : n - 1;
  bf16x8 xf[4];
#pragma unroll
  for (int ks = 0; ks < 4; ks++)
    xf[ks] = *reinterpret_cast<const bf16x8*>(Xb + (size_t)mc * 128 + ks * 32 + kgrp * 8);
#pragma unroll
  for (int nt = 0; nt < 8; nt++) {
    f32x4 acc = {0.f, 0.f, 0.f, 0.f};
#pragma unroll
    for (int ks = 0; ks < 4; ks++) {
      bf16x8 wf = *reinterpret_cast<const bf16x8*>(W0t + (size_t)(nt * 16 + l15) * 128 + ks * 32 + kgrp * 8);
      acc = __builtin_amdgcn_mfma_f32_16x16x32_bf16(wf, xf[ks], acc, 0, 0, 0);
    }
    int ncol = nt * 16 + kgrp * 4;
    ushort4 p = *reinterpret_cast<const ushort4*>(Prev + (size_t)mc * 128 + ncol);
    float4 bv = *reinterpret_cast<const float4*>(b1 + ncol);
    acc[0] = fmaxf(acc[0] + b2f(p.x) + bv.x, 0.f);
    acc[1] = fmaxf(acc[1] + b2f(p.y) + bv.y, 0.f);
    acc[2] = fmaxf(acc[2] + b2f(p.z) + bv.z, 0.f);
    acc[3] = fmaxf(acc[3] + b2f(p.w) + bv.w, 0.f);
    ushort4 st; st.x = f2bf(acc[0]); st.y = f2bf(acc[1]); st.z = f2bf(acc[2]); st.w = f2bf(acc[3]);
    *reinterpret_cast<ushort4*>(&sp[wid][l15][ncol]) = st;
  }
  __syncthreads();
#pragma unroll
  for (int nt = 0; nt < 4; nt++) {
    f32x4 acc = {0.f, 0.f, 0.f, 0.f};
#pragma unroll
    for (int ks = 0; ks < 4; ks++) {
      bf16x8 af = *reinterpret_cast<const bf16x8*>(W2t + (size_t)(nt * 16 + l15) * 128 + ks * 32 + kgrp * 8);
      bf16x8 bf = *reinterpret_cast<const bf16x8*>(&sp[wid][l15][ks * 32 + kgrp * 8]);
      acc = __builtin_amdgcn_mfma_f32_16x16x32_bf16(af, bf, acc, 0, 0, 0);
    }
    if (m < n) {
      int c = nt * 16 + kgrp * 4;
      ushort4 st; st.x = f2bf(acc[0]); st.y = f2bf(acc[1]); st.z = f2bf(acc[2]); st.w = f2bf(acc[3]);
      *reinterpret_cast<ushort4*>(GB + (size_t)m * 64 + c) = st;
    }
  }
}

// ---------------- SpMM D=128 bf16: 16 lanes/node, 16 nodes/block, unroll-8 ----------------
__global__ __launch_bounds__(256) void spmm128c_k(const ushort* __restrict__ hin, ushort* __restrict__ hout,
                                                  const int* __restrict__ rowptr, const int2* __restrict__ ev,
                                                  int n) {
  int grp = threadIdx.x >> 4;   // 16 groups
  int gl  = threadIdx.x & 15;   // lane in group: 16B of the 256B row
  int node = blockIdx.x * 16 + grp;
  if (node >= n) return;
  int e0 = rowptr[node], e1 = rowptr[node + 1];
  float a0 = 0.f, a1 = 0.f, a2 = 0.f, a3 = 0.f, a4 = 0.f, a5 = 0.f, a6 = 0.f, a7 = 0.f;
  for (int ee = e0; ee < e1; ee += 8) {
    int2 ed[8];
#pragma unroll
    for (int j = 0; j < 8; j++) {
      int idx = ee + j;
      int2 t = ev[idx < e1 ? idx : e0];
      if (idx >= e1) t.y = 0;
      ed[j] = t;
    }
    uint4 v[8];
#pragma unroll
    for (int j = 0; j < 8; j++)
      v[j] = *reinterpret_cast<const uint4*>(hin + (size_t)ed[j].x * 128 + gl * 8);
#pragma unroll
    for (int j = 0; j < 8; j++) {
      float w = __int_as_float(ed[j].y);
      a0 = fmaf(w, bfl(v[j].x), a0); a1 = fmaf(w, bfh(v[j].x), a1);
      a2 = fmaf(w, bfl(v[j].y), a2); a3 = fmaf(w, bfh(v[j].y), a3);
      a4 = fmaf(w, bfl(v[j].z), a4); a5 = fmaf(w, bfh(v[j].z), a5);
      a6 = fmaf(w, bfl(v[j].w), a6); a7 = fmaf(w, bfh(v[j].w), a7);
    }
  }
  uint4 st;
  st.x = (uint)f2bf(a0) | ((uint)f2bf(a1) << 16);
  st.y = (uint)f2bf(a2) | ((uint)f2bf(a3) << 16);
  st.z = (uint)f2bf(a4) | ((uint)f2bf(a5) << 16);
  st.w = (uint)f2bf(a6) | ((uint)f2bf(a7) << 16);
  *reinterpret_cast<uint4*>(hout + (size_t)node * 128 + gl * 8) = st;
}

// ---------------- SpMM D=16 bf16 (8 threads/node, 2 cols each) ----------------
__global__ __launch_bounds__(256) void spmm16b_k(
    const ushort* __restrict__ in, int instride, int ioff,
    const ushort* __restrict__ add, int addstride, int aoff,
    const float* __restrict__ b2, float* __restrict__ outf, ushort* __restrict__ outb,
    const int* __restrict__ rowptr, const int2* __restrict__ ev, int n) {
  int t = blockIdx.x * 256 + threadIdx.x;
  int node = t >> 3, cp = t & 7;
  if (node >= n) return;
  int e0 = rowptr[node], e1 = rowptr[node + 1];
  float a0 = 0.f, a1 = 0.f;
  for (int ee = e0; ee < e1; ee += 4) {
    int2 ed[4];
#pragma unroll
    for (int j = 0; j < 4; j++) {
      int idx = ee + j;
      int2 tt = ev[idx < e1 ? idx : e0];
      if (idx >= e1) tt.y = 0;
      ed[j] = tt;
    }
    uint v[4];
#pragma unroll
    for (int j = 0; j < 4; j++)
      v[j] = *reinterpret_cast<const uint*>(in + (size_t)ed[j].x * instride + ioff + cp * 2);
#pragma unroll
    for (int j = 0; j < 4; j++) {
      float wt = __int_as_float(ed[j].y);
      a0 = fmaf(wt, bfl(v[j]), a0); a1 = fmaf(wt, bfh(v[j]), a1);
    }
  }
  uint av = *reinterpret_cast<const uint*>(add + (size_t)node * addstride + aoff + cp * 2);
  a0 += bfl(av); a1 += bfh(av);
  if (outf) {
    float2 st; st.x = a0 + b2[cp * 2]; st.y = a1 + b2[cp * 2 + 1];
    *reinterpret_cast<float2*>(outf + (size_t)node * 16 + cp * 2) = st;
  } else {
    uint pk = (uint)f2bf(a0) | ((uint)f2bf(a1) << 16);
    *reinterpret_cast<uint*>(outb + (size_t)node * 16 + cp * 2) = pk;
  }
}

extern "C" void kernel_launch(void* const* d_in, const int* in_sizes, int n_in,
                              void* d_out, int out_size, void* d_ws, size_t ws_size,
                              hipStream_t stream) {
  const float* x  = (const float*)d_in[0];
  const int*   ei = (const int*)d_in[1];
  const float* W1 = (const float*)d_in[2];
  const float* b1 = (const float*)d_in[3];
  const float* W2 = (const float*)d_in[4];
  const float* b2 = (const float*)d_in[5];
  float* out = (float*)d_out;

  const int n = in_sizes[0] / DF;
  const int e = in_sizes[1] / 2;
  const int* srcp = ei;
  const int* dstp = ei + e;

  char* ws = (char*)d_ws;
  size_t off = 0;
  auto alloc = [&](size_t bytes) -> void* {
    void* p = ws + off;
    off += (bytes + 255) & ~(size_t)255;
    return p;
  };
  ushort* Xb    = (ushort*)alloc((size_t)n * DF * 2);   // x bf16; later F0/F1
  ushort* U     = (ushort*)alloc((size_t)n * DF * 2);   // feature ping; later GB
  ushort* T     = (ushort*)alloc((size_t)n * DF * 2);   // feature pong
  int*   deg    = (int*)alloc((size_t)n * 4);
  float* dis    = (float*)alloc((size_t)n * 4);
  int*   rowptr = (int*)alloc((size_t)(n + 1) * 4);
  int*   rank   = (int*)alloc((size_t)e * 4);
  int*   partials = (int*)alloc(1024 * 4);
  int2*  ev     = (int2*)alloc((size_t)e * 8);
  ushort* W1t   = (ushort*)alloc(4 * 128 * 128 * 2);
  ushort* W2t   = (ushort*)alloc(64 * 128 * 2);
  // aliases (dead buffers reused)
  ushort* GB = U;                        // n x 64 bf16 (U dead after gemm_last inputs read)
  ushort* F0 = Xb;                       // n x 16 bf16 (Xb dead after gemm_last)
  ushort* F1 = Xb + (size_t)n * 16;      // n x 16 bf16

  hipMemsetAsync(deg, 0, (size_t)n * 4, stream);

  int gE = (e + 255) / 256;
  int gN = (n + 255) / 256;
  int nb = (n + 1023) / 1024;

  deg_hist_k<<<gE, 256, 0, stream>>>(dstp, e, deg, rank);
  dis_k<<<gN, 256, 0, stream>>>(deg, n, dis);
  scan1_k<<<nb, 256, 0, stream>>>(deg, n, partials);
  scan2_k<<<1, 64, 0, stream>>>(partials, nb);
  scan3_k<<<nb, 256, 0, stream>>>(deg, n, e, partials, rowptr);
  csr_fill_k<<<gE, 256, 0, stream>>>(srcp, dstp, e, rank, rowptr, dis, ev);

  castx_k<<<(n * 32 + 255) / 256, 256, 0, stream>>>(x, Xb, n * 32);
  prepw_k<<<256, 256, 0, stream>>>(W1, W2, W1t, W2t);

  int gGemm = (n + 63) / 64;
  int gSpmm = (n + 15) / 16;
  int gS16  = (n * 8 + 255) / 256;

  // ----- Layer 1 Horner: z3 -> A -> +z2 -> A -> +z1 -> A -> last(relu,+b1, GB) -----
  gemm128b_k<<<gGemm, 256, 0, stream>>>(Xb, W1t + 3 * DF * DF, nullptr, U, n, 0);
  spmm128c_k<<<gSpmm, 256, 0, stream>>>(U, T, rowptr, ev, n);
  gemm128b_k<<<gGemm, 256, 0, stream>>>(Xb, W1t + 2 * DF * DF, T, U, n, 1);
  spmm128c_k<<<gSpmm, 256, 0, stream>>>(U, T, rowptr, ev, n);
  gemm128b_k<<<gGemm, 256, 0, stream>>>(Xb, W1t + 1 * DF * DF, T, U, n, 1);
  spmm128c_k<<<gSpmm, 256, 0, stream>>>(U, T, rowptr, ev, n);
  gemm_last_k<<<gGemm, 256, 0, stream>>>(Xb, W1t, T, b1, W2t, GB, n);

  // ----- Layer 2 Horner at D=16 (bf16 chain) -----
  spmm16b_k<<<gS16, 256, 0, stream>>>(GB, 64, 48, GB, 64, 32, nullptr, nullptr, F0, rowptr, ev, n);
  spmm16b_k<<<gS16, 256, 0, stream>>>(F0, 16, 0,  GB, 64, 16, nullptr, nullptr, F1, rowptr, ev, n);
  spmm16b_k<<<gS16, 256, 0, stream>>>(F1, 16, 0,  GB, 64, 0,  b2, out, nullptr, rowptr, ev, n);
}